// Round 7
// baseline (205.186 us; speedup 1.0000x reference)
//
#include <hip/hip_runtime.h>
#include <hip/hip_fp16.h>

#define EMB_D 64
#define SB 1024     // scan block size
#define SPAN 128    // nodes per group (pow2: group = dst>>7, local = dst&127)
#define MAXG 1024   // max groups for LDS arrays
#define MAXK 3072   // max (group,slice) keys for Tier A7 LDS arrays
#define NCHUNK2 512 // edge chunks
#define CHMAX 4096  // max edges per chunk for LDS record buffer (32 KB)
#define TILE 4096   // gather_fused tile (records)
#define SLICE_SH 14 // src-slice: 16384 rows = 2 MB of emb16 per slice
#define CAST_BLOCKS 256

// ===========================================================================
// Tier A7: A6 + src-slice-sorted streams for L2 band phasing.
//   A1K: fused fp16 cast + per-chunk (group,slice)-key histogram
//   scan: reduce + multi-pass partials + IN-PLACE apply over [NK][NCHUNK2]
//   PSK: per-chunk LDS counting sort by key; counts derived as adjacent
//        diffs of scanT (no extra array, no hist rebuild)
//   GF : gather_fused (R6): per-node lists now slice-ascending; all 554
//        blocks co-resident (2/CU) -> concurrent walkers sweep the 9 MB
//        row table in phase -> per-XCD working set ~2-4 MB (L2-resident).
// Tier A6: group-key path (proven 175 us). Tier C: atomic scatter.
// R4 lesson: LDS-atomic accumulation ~100x too slow. R6 lesson: gather is
// L2-miss-bound (147 MB @ ~3 TB/s); register accumulation + MLP is right.
// ===========================================================================

__device__ __forceinline__ float h15_to_float(unsigned int bits) {
    return __half2float(__ushort_as_half((unsigned short)bits));
}

// --- A1K: fused cast + chunked (group,slice) histogram --------------------
__global__ void a1_cast_histK(const float2* __restrict__ embin,
                              __half2* __restrict__ emb16, int n2,
                              const int* __restrict__ src,
                              const int* __restrict__ dst,
                              int* __restrict__ cntT,   // [NK][NCHUNK2]
                              int E, int NK, int S, int chunk) {
    if (blockIdx.x < CAST_BLOCKS) {
        int i = blockIdx.x * blockDim.x + threadIdx.x;
        int st = CAST_BLOCKS * blockDim.x;
        for (; i < n2; i += st)
            emb16[i] = __float22half2_rn(embin[i]);
    } else {
        __shared__ int bins[MAXK];
        int hb = blockIdx.x - CAST_BLOCKS;
        for (int k = threadIdx.x; k < NK; k += blockDim.x) bins[k] = 0;
        __syncthreads();
        int beg = hb * chunk;
        int end = min(beg + chunk, E);
        for (int i = beg + threadIdx.x; i < end; i += blockDim.x) {
            int key = (dst[i] >> 7) * S + (src[i] >> SLICE_SH);
            atomicAdd(&bins[key], 1);
        }
        __syncthreads();
        for (int k = threadIdx.x; k < NK; k += blockDim.x)
            cntT[k * NCHUNK2 + hb] = bins[k];
    }
}

// --- A1: fused cast + chunked group histogram (Tier A6) -------------------
__global__ void a1_cast_hist(const float2* __restrict__ embin,
                             __half2* __restrict__ emb16, int n2,
                             const int* __restrict__ dst,
                             int* __restrict__ cntT,   // [G][NCHUNK2]
                             int E, int G, int chunk) {
    if (blockIdx.x < CAST_BLOCKS) {
        int i = blockIdx.x * blockDim.x + threadIdx.x;
        int st = CAST_BLOCKS * blockDim.x;
        for (; i < n2; i += st)
            emb16[i] = __float22half2_rn(embin[i]);
    } else {
        __shared__ int bins[MAXG];
        int hb = blockIdx.x - CAST_BLOCKS;
        for (int g = threadIdx.x; g < G; g += blockDim.x) bins[g] = 0;
        __syncthreads();
        int beg = hb * chunk;
        int end = min(beg + chunk, E);
        for (int i = beg + threadIdx.x; i < end; i += blockDim.x)
            atomicAdd(&bins[dst[i] >> 7], 1);
        __syncthreads();
        for (int g = threadIdx.x; g < G; g += blockDim.x)
            cntT[g * NCHUNK2 + hb] = bins[g];
    }
}

// --- generic 3-phase exclusive scan ---------------------------------------
__global__ void scan_reduceB(const int* __restrict__ counts,
                             int* __restrict__ partial, int M) {
    __shared__ int wsum[16];
    const int tid = threadIdx.x, lane = tid & 63, wid = tid >> 6;
    int i = blockIdx.x * SB + tid;
    int v = (i < M) ? counts[i] : 0;
    #pragma unroll
    for (int off = 32; off > 0; off >>= 1)
        v += __shfl_xor(v, off, 64);
    if (lane == 0) wsum[wid] = v;
    __syncthreads();
    if (tid == 0) {
        int s = 0;
        #pragma unroll
        for (int k = 0; k < 16; ++k) s += wsum[k];
        partial[blockIdx.x] = s;
    }
}

// multi-pass: handles any numB (sequential 1024-wide scans w/ carry)
__global__ void scan_partials(const int* __restrict__ partial,
                              int* __restrict__ blockoff,
                              int* __restrict__ offsets, int numB, int M) {
    __shared__ int wsum[16];
    __shared__ int wpre[16];
    __shared__ int carry;
    const int tid = threadIdx.x, lane = tid & 63, wid = tid >> 6;
    if (tid == 0) carry = 0;
    const int nPass = (numB + SB - 1) / SB;
    for (int p = 0; p < nPass; ++p) {
        __syncthreads();
        int base = carry;
        int idx = p * SB + tid;
        int v = (idx < numB) ? partial[idx] : 0;
        int x = v;
        #pragma unroll
        for (int off = 1; off < 64; off <<= 1) {
            int t = __shfl_up(x, off, 64);
            if (lane >= off) x += t;
        }
        if (lane == 63) wsum[wid] = x;
        __syncthreads();
        if (wid == 0) {
            int s = (lane < 16) ? wsum[lane] : 0;
            #pragma unroll
            for (int off = 1; off < 16; off <<= 1) {
                int t = __shfl_up(s, off, 64);
                if (lane >= off) s += t;
            }
            if (lane < 16) wpre[lane] = s;
        }
        __syncthreads();
        int excl = base + ((wid > 0) ? wpre[wid - 1] : 0) + (x - v);
        if (idx < numB) blockoff[idx] = excl;
        __syncthreads();
        if (tid == 0) carry = base + wpre[15];
    }
    __syncthreads();
    if (tid == 0) offsets[M] = carry;   // grand total = E
}

__global__ void scan_applyB(const int* __restrict__ counts,
                            const int* __restrict__ blockoff,
                            int* __restrict__ offsets, int M) {
    __shared__ int wsum[16];
    __shared__ int wpre[16];
    const int tid = threadIdx.x, lane = tid & 63, wid = tid >> 6;
    int i = blockIdx.x * SB + tid;
    int v = (i < M) ? counts[i] : 0;
    int x = v;
    #pragma unroll
    for (int off = 1; off < 64; off <<= 1) {
        int t = __shfl_up(x, off, 64);
        if (lane >= off) x += t;
    }
    if (lane == 63) wsum[wid] = x;
    __syncthreads();
    if (wid == 0) {
        int s = (lane < 16) ? wsum[lane] : 0;
        #pragma unroll
        for (int off = 1; off < 16; off <<= 1) {
            int t = __shfl_up(s, off, 64);
            if (lane >= off) s += t;
        }
        if (lane < 16) wpre[lane] = s;
    }
    __syncthreads();
    int excl = blockoff[blockIdx.x] + ((wid > 0) ? wpre[wid - 1] : 0) + (x - v);
    if (i < M) offsets[i] = excl;
}

// in-place variant: data[i] <- exclusive_scan(data)[i]
__global__ void scan_apply_ip(int* __restrict__ data,
                              const int* __restrict__ blockoff, int M) {
    __shared__ int wsum[16];
    __shared__ int wpre[16];
    const int tid = threadIdx.x, lane = tid & 63, wid = tid >> 6;
    int i = blockIdx.x * SB + tid;
    int v = (i < M) ? data[i] : 0;
    int x = v;
    #pragma unroll
    for (int off = 1; off < 64; off <<= 1) {
        int t = __shfl_up(x, off, 64);
        if (lane >= off) x += t;
    }
    if (lane == 63) wsum[wid] = x;
    __syncthreads();
    if (wid == 0) {
        int s = (lane < 16) ? wsum[lane] : 0;
        #pragma unroll
        for (int off = 1; off < 16; off <<= 1) {
            int t = __shfl_up(s, off, 64);
            if (lane >= off) s += t;
        }
        if (lane < 16) wpre[lane] = s;
    }
    __syncthreads();
    int excl = blockoff[blockIdx.x] + ((wid > 0) ? wpre[wid - 1] : 0) + (x - v);
    if (i < M) data[i] = excl;
}

// --- PSK: per-chunk LDS counting sort by (group,slice) key ----------------
// counts derived as adjacent diffs of flattened exclusive scanT.
__global__ __launch_bounds__(512) void partition_sortK(
        const int* __restrict__ src,
        const int* __restrict__ dst,
        const float* __restrict__ w,
        const int* __restrict__ scanT,   // [NK*NCHUNK2+1] scanned in place
        uint2* __restrict__ stream8,     // [E]
        int E, int NK, int S, int chunk) {
    __shared__ uint2 recs[CHMAX];        // 32 KB
    __shared__ int cur[MAXK];            // 12 KB
    __shared__ int delta[MAXK];          // 12 KB
    __shared__ int wtot[8];

    const int tid = threadIdx.x, lane = tid & 63, wv = tid >> 6;
    const int b = blockIdx.x;
    const int beg = b * chunk;
    const int end = min(beg + chunk, E);
    const int n = end - beg;

    const int K = (NK + 511) >> 9;       // <= 6 (NK <= MAXK)
    int vals[6], bases[6];
    int acc = 0;
    #pragma unroll
    for (int k = 0; k < 6; ++k) {
        int key = tid * K + k;
        int c = 0, bs = 0;
        if (k < K && key < NK) {
            bs = scanT[key * NCHUNK2 + b];
            c = scanT[key * NCHUNK2 + b + 1] - bs;   // flattened-scan diff
        }
        vals[k] = c;
        bases[k] = bs;
        acc += c;
    }
    int x = acc;
    #pragma unroll
    for (int off = 1; off < 64; off <<= 1) {
        int t = __shfl_up(x, off, 64);
        if (lane >= off) x += t;
    }
    if (lane == 63) wtot[wv] = x;
    __syncthreads();
    int woff = 0;
    #pragma unroll
    for (int k2 = 0; k2 < 8; ++k2)
        woff += (k2 < wv) ? wtot[k2] : 0;
    int run = woff + x - acc;            // exclusive prefix (local base)
    #pragma unroll
    for (int k = 0; k < 6; ++k) {
        int key = tid * K + k;
        if (k < K && key < NK) {
            cur[key] = run;
            delta[key] = bases[k] - run;
            run += vals[k];
        }
    }
    __syncthreads();

    for (int i = beg + tid; i < end; i += 512) {
        int d = dst[i];
        int key = (d >> 7) * S + (src[i] >> SLICE_SH);
        unsigned int wb = __half_as_ushort(__float2half_rn(w[i]));
        unsigned int pk = ((unsigned int)src[i] << 15) | (wb & 0x7FFFu);
        int j = atomicAdd(&cur[key], 1);
        recs[j] = make_uint2(pk, (unsigned int)(d & (SPAN - 1)) |
                                 ((unsigned int)key << 7));
    }
    __syncthreads();

    for (int j = tid; j < n; j += 512) {
        uint2 r = recs[j];
        int key = (int)(r.y >> 7);
        stream8[delta[key] + j] = make_uint2(r.x, r.y & (SPAN - 1u));
    }
}

// --- PS: per-chunk LDS counting sort by group (Tier A6) -------------------
__global__ __launch_bounds__(512) void partition_sort(
        const int* __restrict__ src,
        const int* __restrict__ dst,
        const float* __restrict__ w,
        const int* __restrict__ cntT,    // [G][NCHUNK2]
        const int* __restrict__ scanT,   // [G*NCHUNK2+1]
        uint2* __restrict__ stream8,     // [E]
        int E, int G, int chunk) {
    __shared__ uint2 recs[CHMAX];        // 32 KB
    __shared__ int cur[MAXG];
    __shared__ int delta[MAXG];
    __shared__ int wtot[8];

    const int tid = threadIdx.x, lane = tid & 63, wv = tid >> 6;
    const int b = blockIdx.x;
    const int beg = b * chunk;
    const int end = min(beg + chunk, E);
    const int n = end - beg;

    const int K = (G + 511) >> 9;        // <= 2
    int vals[2];
    int acc = 0;
    #pragma unroll
    for (int k = 0; k < 2; ++k) {
        int g = tid * K + k;
        int c = (k < K && g < G) ? cntT[g * NCHUNK2 + b] : 0;
        vals[k] = c;
        acc += c;
    }
    int x = acc;
    #pragma unroll
    for (int off = 1; off < 64; off <<= 1) {
        int t = __shfl_up(x, off, 64);
        if (lane >= off) x += t;
    }
    if (lane == 63) wtot[wv] = x;
    __syncthreads();
    int woff = 0;
    #pragma unroll
    for (int k2 = 0; k2 < 8; ++k2)
        woff += (k2 < wv) ? wtot[k2] : 0;
    int run = woff + x - acc;
    #pragma unroll
    for (int k = 0; k < 2; ++k) {
        int g = tid * K + k;
        if (k < K && g < G) {
            cur[g] = run;
            delta[g] = scanT[g * NCHUNK2 + b] - run;
            run += vals[k];
        }
    }
    __syncthreads();

    for (int i = beg + tid; i < end; i += 512) {
        int d = dst[i];
        unsigned int wb = __half_as_ushort(__float2half_rn(w[i]));
        unsigned int pk = ((unsigned int)src[i] << 15) | (wb & 0x7FFFu);
        int g = d >> 7;
        int j = atomicAdd(&cur[g], 1);
        recs[j] = make_uint2(pk, (unsigned int)(d & (SPAN - 1)) |
                                 ((unsigned int)g << 7));
    }
    __syncthreads();

    for (int j = tid; j < n; j += 512) {
        uint2 r = recs[j];
        int g = (int)(r.y >> 7);
        stream8[delta[g] + j] = make_uint2(r.x, r.y & (SPAN - 1u));
    }
}

// --- GF: fused per-group CSR + register-accumulate gather + normalize -----
// SN = scanT stride per group (S*NCHUNK2). Crew = 16 lanes owns nodes
// {c, c+32, c+64, c+96}; two 8-lane substreams, uint4 rows, 2-deep each.
__global__ __launch_bounds__(512) void gather_fused(
        const char* __restrict__ emb16b,      // row v at byte v*128
        const uint2* __restrict__ stream8,    // [E] {pk, dl}
        const int* __restrict__ scanT,
        float* __restrict__ out, int N, int SN) {
    __shared__ uint2 lrec[TILE];              // 32 KB
    __shared__ unsigned int srt[TILE];        // 16 KB
    __shared__ int hcnt[SPAN];
    __shared__ int nstart[SPAN];
    __shared__ int cur[SPAN];
    __shared__ int wtot[2];

    const int g = blockIdx.x;
    const int tid = threadIdx.x;
    const int lane = tid & 63, wv = tid >> 6;
    const int base = scanT[(size_t)g * SN];
    const int endE = scanT[(size_t)(g + 1) * SN];
    const int crew = tid >> 4;                   // 0..31
    const int ql = tid & 15;
    const int sub = ql >> 3;                     // substream 0/1
    const int sl = ql & 7;                       // 16B segment of row
    const unsigned qlo = (unsigned)(sl << 4);

    float4 accA[4], accB[4];                  // dims sl*8+0..3 / +4..7
    #pragma unroll
    for (int ni = 0; ni < 4; ++ni) {
        accA[ni] = make_float4(0.f, 0.f, 0.f, 0.f);
        accB[ni] = make_float4(0.f, 0.f, 0.f, 0.f);
    }

    for (int tb = base; tb < endE; tb += TILE) {
        const int n = min(TILE, endE - tb);
        if (tid < SPAN) hcnt[tid] = 0;
        __syncthreads();
        for (int j = tid; j < n; j += 512) {
            uint2 r = stream8[tb + j];
            lrec[j] = r;
            atomicAdd(&hcnt[r.y], 1);
        }
        __syncthreads();
        int v = (tid < SPAN) ? hcnt[tid] : 0;
        int x = v;
        #pragma unroll
        for (int off = 1; off < 64; off <<= 1) {
            int t = __shfl_up(x, off, 64);
            if (lane >= off) x += t;
        }
        if (wv < 2 && lane == 63) wtot[wv] = x;
        __syncthreads();
        if (tid < SPAN) {
            int excl = x - v + ((wv == 1) ? wtot[0] : 0);
            nstart[tid] = excl;
            cur[tid] = excl;
        }
        __syncthreads();
        for (int j = tid; j < n; j += 512) {
            uint2 r = lrec[j];
            int slot = atomicAdd(&cur[r.y], 1);
            srt[slot] = r.x;
        }
        __syncthreads();
        #pragma unroll
        for (int ni = 0; ni < 4; ++ni) {
            int nd = crew + (ni << 5);
            int s = nstart[nd];
            int e = cur[nd];
            float4 aA = accA[ni];
            float4 aB = accB[ni];
            int k0 = s + sub;
            unsigned int pk0 = (k0 < e) ? srt[k0] : 0u;
            uint4 r0 = *reinterpret_cast<const uint4*>(
                emb16b + ((pk0 >> 15) * 128u + qlo));
            for (int k = k0; k < e; k += 2) {
                int k1 = k + 2;
                unsigned int pk1 = (k1 < e) ? srt[k1] : 0u;
                uint4 r1 = *reinterpret_cast<const uint4*>(
                    emb16b + ((pk1 >> 15) * 128u + qlo));
                float wt = h15_to_float(pk0 & 0x7FFFu);
                float2 x01 = __half22float2(*reinterpret_cast<__half2*>(&r0.x));
                float2 x23 = __half22float2(*reinterpret_cast<__half2*>(&r0.y));
                float2 x45 = __half22float2(*reinterpret_cast<__half2*>(&r0.z));
                float2 x67 = __half22float2(*reinterpret_cast<__half2*>(&r0.w));
                aA.x = fmaf(x01.x, wt, aA.x);
                aA.y = fmaf(x01.y, wt, aA.y);
                aA.z = fmaf(x23.x, wt, aA.z);
                aA.w = fmaf(x23.y, wt, aA.w);
                aB.x = fmaf(x45.x, wt, aB.x);
                aB.y = fmaf(x45.y, wt, aB.y);
                aB.z = fmaf(x67.x, wt, aB.z);
                aB.w = fmaf(x67.y, wt, aB.w);
                pk0 = pk1; r0 = r1;
            }
            accA[ni] = aA;
            accB[ni] = aB;
        }
        __syncthreads();
    }

    #pragma unroll
    for (int ni = 0; ni < 4; ++ni) {
        accA[ni].x += __shfl_xor(accA[ni].x, 8, 64);
        accA[ni].y += __shfl_xor(accA[ni].y, 8, 64);
        accA[ni].z += __shfl_xor(accA[ni].z, 8, 64);
        accA[ni].w += __shfl_xor(accA[ni].w, 8, 64);
        accB[ni].x += __shfl_xor(accB[ni].x, 8, 64);
        accB[ni].y += __shfl_xor(accB[ni].y, 8, 64);
        accB[ni].z += __shfl_xor(accB[ni].z, 8, 64);
        accB[ni].w += __shfl_xor(accB[ni].w, 8, 64);
        int node = g * SPAN + crew + (ni << 5);
        float4 aA = accA[ni];
        float4 aB = accB[ni];
        float ss = aA.x * aA.x + aA.y * aA.y + aA.z * aA.z + aA.w * aA.w
                 + aB.x * aB.x + aB.y * aB.y + aB.z * aB.z + aB.w * aB.w;
        ss += __shfl_xor(ss, 1, 64);
        ss += __shfl_xor(ss, 2, 64);
        ss += __shfl_xor(ss, 4, 64);
        float scale = 1.0f / fmaxf(sqrtf(ss), 1e-12f);
        if (node < N) {
            float4 a = sub ? aB : aA;
            float4 o = make_float4(a.x * scale, a.y * scale,
                                   a.z * scale, a.w * scale);
            *reinterpret_cast<float4*>(out + (size_t)node * EMB_D
                                       + (sl << 3) + (sub << 2)) = o;
        }
    }
}

// ===========================================================================
// Tier C: atomic scatter fallback.
// ===========================================================================
__global__ void lightgcn_scatter(const float* __restrict__ emb,
                                 const float* __restrict__ w,
                                 const int* __restrict__ src,
                                 const int* __restrict__ dst,
                                 float* __restrict__ h, int E) {
    long long t = (long long)blockIdx.x * blockDim.x + threadIdx.x;
    int e = (int)(t >> 4);
    int d = (int)(t & 15) << 2;
    if (e >= E) return;
    int s = src[e]; int v = dst[e]; float wt = w[e];
    const float4 m = *reinterpret_cast<const float4*>(emb + (size_t)s * EMB_D + d);
    float* o = h + (size_t)v * EMB_D + d;
    unsafeAtomicAdd(o + 0, m.x * wt);
    unsafeAtomicAdd(o + 1, m.y * wt);
    unsafeAtomicAdd(o + 2, m.z * wt);
    unsafeAtomicAdd(o + 3, m.w * wt);
}

__global__ void lightgcn_normalize(float* __restrict__ h, int N) {
    int row = blockIdx.x * (blockDim.x >> 6) + (threadIdx.x >> 6);
    int lane = threadIdx.x & 63;
    if (row >= N) return;
    float x = h[(size_t)row * EMB_D + lane];
    float ss = x * x;
    #pragma unroll
    for (int off = 32; off > 0; off >>= 1)
        ss += __shfl_xor(ss, off, 64);
    h[(size_t)row * EMB_D + lane] = x / fmaxf(sqrtf(ss), 1e-12f);
}

extern "C" void kernel_launch(void* const* d_in, const int* in_sizes, int n_in,
                              void* d_out, int out_size, void* d_ws, size_t ws_size,
                              hipStream_t stream) {
    const float* emb = (const float*)d_in[0];   // [N, 64] fp32
    const float* w   = (const float*)d_in[1];   // [E] fp32
    const int*   src = (const int*)d_in[2];     // [E] int32
    const int*   dst = (const int*)d_in[3];     // [E] int32
    float* out = (float*)d_out;

    const int N = in_sizes[0] / EMB_D;
    const int E = in_sizes[1];
    const int block = 256;
    const int G = (N + SPAN - 1) / SPAN;

    // ---- Tier A7 workspace: cnt/scanT[M4+1] | partial | blockoff | pad |
    //      stream8[E] uint2 | pad | emb16  (~31 MB) ----
    const int S4 = (N + (1 << SLICE_SH) - 1) >> SLICE_SH;
    const int NK4 = G * S4;
    const int M4 = NK4 * NCHUNK2;
    const int numB4 = (M4 + SB - 1) / SB;
    const int chunk4 = (E + NCHUNK2 - 1) / NCHUNK2;
    const int SN4 = S4 * NCHUNK2;
    size_t intsA7 = (size_t)(M4 + 1) + 2 * (size_t)numB4;
    size_t strOff7 = (intsA7 * sizeof(int) + 15) & ~(size_t)15;
    size_t embOff7 = (strOff7 + (size_t)E * sizeof(uint2) + 15) & ~(size_t)15;
    size_t neededA7 = embOff7 + (size_t)N * EMB_D * sizeof(__half);

    // ---- Tier A6 workspace (~27.4 MB) ----
    const int M3 = G * NCHUNK2;
    const int numB3 = (M3 + SB - 1) / SB;
    const int chunk3 = (E + NCHUNK2 - 1) / NCHUNK2;
    size_t intsA5 = (size_t)M3 + (size_t)(M3 + 1) + 2 * (size_t)numB3;
    size_t strOff5 = (intsA5 * sizeof(int) + 15) & ~(size_t)15;
    size_t embOff5 = (strOff5 + (size_t)E * sizeof(uint2) + 15) & ~(size_t)15;
    size_t neededA5 = embOff5 + (size_t)N * EMB_D * sizeof(__half);

    if (ws_size >= neededA7 && NK4 <= MAXK && chunk4 <= CHMAX &&
        E < (1 << 28) && N < (1 << 17)) {
        int* cntT     = (int*)d_ws;              // M4+1 (becomes scanT)
        int* partial  = cntT + M4 + 1;           // numB4
        int* blockoff = partial + numB4;         // numB4
        uint2* stream8 = (uint2*)((char*)d_ws + strOff7);   // E
        __half2* emb16 = (__half2*)((char*)d_ws + embOff7);

        int n2 = N * (EMB_D / 2);

        a1_cast_histK<<<CAST_BLOCKS + NCHUNK2, block, 0, stream>>>(
            (const float2*)emb, emb16, n2, src, dst, cntT, E, NK4, S4, chunk4);

        scan_reduceB<<<numB4, SB, 0, stream>>>(cntT, partial, M4);
        scan_partials<<<1, SB, 0, stream>>>(partial, blockoff, cntT, numB4, M4);
        scan_apply_ip<<<numB4, SB, 0, stream>>>(cntT, blockoff, M4);

        partition_sortK<<<NCHUNK2, 512, 0, stream>>>(src, dst, w, cntT,
                                                     stream8, E, NK4, S4,
                                                     chunk4);
        gather_fused<<<G, 512, 0, stream>>>((const char*)emb16, stream8, cntT,
                                            out, N, SN4);
    } else if (ws_size >= neededA5 && G <= MAXG && chunk3 <= CHMAX &&
               E < (1 << 28) && N < (1 << 17)) {
        int* cntT     = (int*)d_ws;              // M3
        int* scanT    = cntT + M3;               // M3+1
        int* partial  = scanT + M3 + 1;          // numB3
        int* blockoff = partial + numB3;         // numB3
        uint2* stream8 = (uint2*)((char*)d_ws + strOff5);   // E
        __half2* emb16 = (__half2*)((char*)d_ws + embOff5);

        int n2 = N * (EMB_D / 2);

        a1_cast_hist<<<CAST_BLOCKS + NCHUNK2, block, 0, stream>>>(
            (const float2*)emb, emb16, n2, dst, cntT, E, G, chunk3);

        scan_reduceB<<<numB3, SB, 0, stream>>>(cntT, partial, M3);
        scan_partials<<<1, SB, 0, stream>>>(partial, blockoff, scanT, numB3, M3);
        scan_applyB<<<numB3, SB, 0, stream>>>(cntT, blockoff, scanT, M3);

        partition_sort<<<NCHUNK2, 512, 0, stream>>>(src, dst, w, cntT, scanT,
                                                    stream8, E, G, chunk3);

        gather_fused<<<G, 512, 0, stream>>>((const char*)emb16, stream8,
                                            scanT, out, N, NCHUNK2);
    } else {
        hipMemsetAsync(d_out, 0, (size_t)out_size * sizeof(float), stream);
        long long total = (long long)E * 16;
        int grid = (int)((total + block - 1) / block);
        lightgcn_scatter<<<grid, block, 0, stream>>>(emb, w, src, dst, out, E);
        int gridN = (N + 3) / 4;
        lightgcn_normalize<<<gridN, 256, 0, stream>>>(out, N);
    }
}